// Round 8
// baseline (98.163 us; speedup 1.0000x reference)
//
#include <hip/hip_runtime.h>
#include <hip/hip_bf16.h>
#include <math.h>

#define NC 195             // number of countries
#define ROWS_PER_BLOCK 128 // 4 waves x 32 rows
#define ROWS_PER_WAVE 32
#define ITERS 8            // 4 rows per wave per iteration

__device__ __forceinline__ float hav_scaled(float lat1, float lon1, float lat2, float lon2) {
    const float d2r = 0.017453292519943295f;
    lat1 *= d2r; lon1 *= d2r; lat2 *= d2r; lon2 *= d2r;
    float sdlat = sinf(0.5f * (lat2 - lat1));
    float sdlon = sinf(0.5f * (lon2 - lon1));
    float a = sdlat * sdlat + cosf(lat1) * cosf(lat2) * sdlon * sdlon;
    a = fminf(fmaxf(a, 0.0f), 1.0f);
    return (2.0f * 6371.0f / 500.0f) * asinf(sqrtf(a));  // 2*R*asin(sqrt(a))/500
}

// Kernel A: 195x195 pairwise scaled distances; also zeroes the arrival counter
// (runs before main_kernel in stream order -> counter==0 guaranteed each call)
__global__ void dist_kernel(const float* __restrict__ coords, float* __restrict__ distm,
                            unsigned int* __restrict__ counter) {
    if (blockIdx.x == 0 && threadIdx.x == 0) *counter = 0u;
    int idx = blockIdx.x * 256 + threadIdx.x;
    if (idx >= NC * NC) return;
    int i = idx / NC;
    int j = idx - i * NC;
    distm[idx] = hav_scaled(coords[2 * i], coords[2 * i + 1],
                            coords[2 * j], coords[2 * j + 1]);
}

// Kernel B: no LDS data staging. 16-lane groups read rows directly from global
// (13 coalesced dword loads), softmax stats in registers + 4-level butterfly.
// Last block (atomic counter) reduces the 2048 partials and writes the mean.
__global__ __launch_bounds__(256) void main_kernel(const float* __restrict__ logits,
                                                   const int* __restrict__ target,
                                                   const float* __restrict__ distm,
                                                   float* __restrict__ partials,
                                                   unsigned int* __restrict__ counter,
                                                   float inv_b,
                                                   float* __restrict__ out) {
    const int t = threadIdx.x;
    const int wave = t >> 6;
    const int lane = t & 63;
    const int u = lane & 15;        // position within 16-lane group
    const int r = lane >> 4;        // row subgroup within wave (0..3)
    const long long wrow0 = (long long)blockIdx.x * ROWS_PER_BLOCK
                          + (long long)wave * ROWS_PER_WAVE;
    float acc = 0.0f;

    for (int i = 0; i < ITERS; ++i) {
        const long long row = wrow0 + i * 4 + r;
        const float* __restrict__ rowp = logits + row * NC;

        // 13 direct global loads: wave = 4 x 64B segments per instr, 4B-aligned
        float x[13];
        #pragma unroll
        for (int k = 0; k < 12; ++k) x[k] = rowp[u + 16 * k];
        x[12] = (u < 3) ? rowp[192 + u] : -INFINITY;

        // lane-local max + argmax (first occurrence: ascending index, strict >)
        float m = x[0]; int mi = u;
        #pragma unroll
        for (int k = 1; k < 13; ++k) {
            if (x[k] > m) { m = x[k]; mi = u + 16 * k; }
        }
        // 4-level butterfly within the 16-lane group; tie-break: smaller index
        #pragma unroll
        for (int off = 8; off > 0; off >>= 1) {
            float om = __shfl_xor(m, off);
            int   oi = __shfl_xor(mi, off);
            if (om > m || (om == m && oi < mi)) { m = om; mi = oi; }
        }
        float s = 0.0f;
        #pragma unroll
        for (int k = 0; k < 13; ++k) s += __expf(x[k] - m);
        #pragma unroll
        for (int off = 8; off > 0; off >>= 1) s += __shfl_xor(s, off);

        if (u == 0) {
            int tg = target[row];
            float ce = (m + __logf(s)) - rowp[tg];   // lse - x_target (row is L1-hot)
            acc += ce + distm[mi * NC + tg];         // distm pre-scaled by 1/500
        }
    }

    __shared__ float wpart[16];
    __shared__ bool amLast;
    if (u == 0) wpart[wave * 4 + r] = acc;
    __syncthreads();
    if (t == 0) {
        float v = 0.0f;
        #pragma unroll
        for (int j = 0; j < 16; ++j) v += wpart[j];
        partials[blockIdx.x] = v;
        __threadfence();                             // release: partial visible device-wide
        unsigned int old = atomicAdd(counter, 1u);   // device-scope
        amLast = (old == gridDim.x - 1);
    }
    __syncthreads();
    if (amLast) {
        __threadfence();                             // acquire: see all partials
        float s = 0.0f;
        #pragma unroll
        for (int j = 0; j < 8; ++j) s += partials[t + 256 * j];   // fixed order -> deterministic
        #pragma unroll
        for (int off = 32; off > 0; off >>= 1) s += __shfl_xor(s, off);
        if (lane == 0) wpart[wave] = s;
        __syncthreads();
        if (t == 0) out[0] = (wpart[0] + wpart[1] + wpart[2] + wpart[3]) * inv_b;
    }
}

extern "C" void kernel_launch(void* const* d_in, const int* in_sizes, int n_in,
                              void* d_out, int out_size, void* d_ws, size_t ws_size,
                              hipStream_t stream) {
    const float* logits = (const float*)d_in[0];
    const int*   target = (const int*)d_in[1];
    const float* coords = (const float*)d_in[2];
    float* out = (float*)d_out;

    const int B = in_sizes[1];                    // 262144
    const int n_blocks = B / ROWS_PER_BLOCK;      // 2048 = 8 blocks/CU exactly

    // ws layout: partials[n_blocks] | counter (16B slot) | distm[195*195]
    float* partials = (float*)d_ws;
    unsigned int* counter = (unsigned int*)(partials + n_blocks);
    float* distm = (float*)(partials + n_blocks + 4);

    dist_kernel<<<(NC * NC + 255) / 256, 256, 0, stream>>>(coords, distm, counter);
    main_kernel<<<n_blocks, 256, 0, stream>>>(logits, target, distm, partials,
                                              counter, 1.0f / (float)B, out);
}